// Round 8
// baseline (1015.564 us; speedup 1.0000x reference)
//
#include <hip/hip_runtime.h>
#include <math.h>

#define DCH 64

// ---------------- CSR build ----------------
// edge_index arrives as int32 (harness converts int64 -> int32):
//   ei[e] = src, ei[E + e] = dst.

__global__ void zero_kernel(int* __restrict__ p, int n) {
    int i = blockIdx.x * blockDim.x + threadIdx.x;
    if (i < n) p[i] = 0;
}

__global__ void hist_kernel(const int* __restrict__ ei, int* __restrict__ cnt, int E) {
    int stride = gridDim.x * blockDim.x;
    for (int e = blockIdx.x * blockDim.x + threadIdx.x; e < E; e += stride) {
        int d = ei[(size_t)E + e];
        atomicAdd(&cnt[d], 1);
    }
}

__global__ void scan1_kernel(const int* __restrict__ cnt, int* __restrict__ offs,
                             int* __restrict__ partial, int n) {
    __shared__ int sh[1024];
    int i = blockIdx.x * 1024 + threadIdx.x;
    int val = (i < n) ? cnt[i] : 0;
    sh[threadIdx.x] = val;
    __syncthreads();
    for (int d = 1; d < 1024; d <<= 1) {
        int t = (threadIdx.x >= d) ? sh[threadIdx.x - d] : 0;
        __syncthreads();
        sh[threadIdx.x] += t;
        __syncthreads();
    }
    if (i < n) offs[i] = sh[threadIdx.x] - val;   // exclusive within block
    if (threadIdx.x == 1023) partial[blockIdx.x] = sh[1023];
}

__global__ void scan2_kernel(int* __restrict__ partial, int* __restrict__ total, int nb) {
    __shared__ int sh[1024];
    int val = (threadIdx.x < nb) ? partial[threadIdx.x] : 0;
    sh[threadIdx.x] = val;
    __syncthreads();
    for (int d = 1; d < 1024; d <<= 1) {
        int t = (threadIdx.x >= d) ? sh[threadIdx.x - d] : 0;
        __syncthreads();
        sh[threadIdx.x] += t;
        __syncthreads();
    }
    if (threadIdx.x < nb) partial[threadIdx.x] = sh[threadIdx.x] - val; // exclusive block offsets
    if (threadIdx.x == 1023) *total = sh[1023];
}

__global__ void scan3_kernel(int* __restrict__ offs, const int* __restrict__ partial, int n) {
    int i = blockIdx.x * 1024 + threadIdx.x;
    if (i < n) offs[i] += partial[blockIdx.x];
}

__global__ void scatter_kernel(const int* __restrict__ ei, const int* __restrict__ offs,
                               int* __restrict__ fill, int* __restrict__ ssrc, int E) {
    int stride = gridDim.x * blockDim.x;
    for (int e = blockIdx.x * blockDim.x + threadIdx.x; e < E; e += stride) {
        int s = ei[e];
        int d = ei[(size_t)E + e];
        int pos = offs[d] + atomicAdd(&fill[d], 1);
        ssrc[pos] = s;
    }
}

// ---------------- fused q/k/v/skip linear ----------------
// block = 256 = 4 waves; wave = matrix, lane = node (64-node chunk per block).
// Per-thread x-row in 64 statically-indexed VGPRs; W row addresses are
// wave-uniform -> s_load broadcast -> v_fmac v,s,v (round-7: FETCH collapsed
// to 16 MB, proving scalarization works). Round-7's flaw: direct stores had
// 64 lanes at 256-B stride per instruction -> partial-sector HBM writes
// (WRITE_SIZE 320 MB vs 102 ideal) + 6 waves/CU -> latency-bound 310 us.
// Fix: stage each wave's 64x64 output tile in LDS (pad 65 -> conflict-light),
// flush with transposed coop-write: each store instr = 4 rows x 256 B = 1 KB
// contiguous. 4 waves/block, 2 blocks/CU (65 KB LDS) = 8 resident waves/CU.

__global__ __launch_bounds__(256, 2)
void linear4_kernel(const float* __restrict__ x,
                    const float* __restrict__ Wq, const float* __restrict__ bq,
                    const float* __restrict__ Wk, const float* __restrict__ bk,
                    const float* __restrict__ Wv, const float* __restrict__ bv,
                    const float* __restrict__ Ws, const float* __restrict__ bs,
                    float* __restrict__ oq, float* __restrict__ ok,
                    float* __restrict__ ov, float* __restrict__ os,
                    int n) {
    __shared__ float tile[4][64][65];
    const int tid = threadIdx.x;
    const int w = tid >> 6;        // wave -> matrix
    const int l = tid & 63;        // lane -> node offset
    const float* W; const float* b; float* o;
    if (w == 0)      { W = Wq; b = bq; o = oq; }
    else if (w == 1) { W = Wk; b = bk; o = ok; }
    else if (w == 2) { W = Wv; b = bv; o = ov; }
    else             { W = Ws; b = bs; o = os; }
    const int base = blockIdx.x * 64;
    const int node = base + l;

    float xr[64];
    if (node < n) {
        const float4* xg = (const float4*)(x + (size_t)node * DCH);
        #pragma unroll
        for (int i = 0; i < 16; ++i) {
            float4 t = xg[i];
            xr[i*4+0] = t.x; xr[i*4+1] = t.y; xr[i*4+2] = t.z; xr[i*4+3] = t.w;
        }
    } else {
        #pragma unroll
        for (int i = 0; i < 64; ++i) xr[i] = 0.f;
    }

    for (int c4 = 0; c4 < 16; ++c4) {
        const float* w0 = W + (c4 * 4 + 0) * DCH;
        const float* w1 = W + (c4 * 4 + 1) * DCH;
        const float* w2 = W + (c4 * 4 + 2) * DCH;
        const float* w3 = W + (c4 * 4 + 3) * DCH;
        float a0 = b[c4*4+0], a1 = b[c4*4+1], a2 = b[c4*4+2], a3 = b[c4*4+3];
        #pragma unroll
        for (int kk = 0; kk < 64; ++kk) {
            float xv = xr[kk];
            a0 += xv * w0[kk];
            a1 += xv * w1[kk];
            a2 += xv * w2[kk];
            a3 += xv * w3[kk];
        }
        tile[w][l][c4*4+0] = a0;
        tile[w][l][c4*4+1] = a1;
        tile[w][l][c4*4+2] = a2;
        tile[w][l][c4*4+3] = a3;
    }
    __syncthreads();
    // transposed coalesced flush: lane = (row-group rb, channel-quad gl);
    // one store instruction covers rows j4*4..j4*4+3 fully = 1 KB contiguous.
    const int gl = l & 15, rb = l >> 4;
    for (int j4 = 0; j4 < 16; ++j4) {
        int row = j4 * 4 + rb;
        int nd = base + row;
        if (nd < n) {
            float4 val = *(const float4*)&tile[w][row][gl * 4];
            *(float4*)&o[(size_t)nd * DCH + gl * 4] = val;
        }
    }
}

// ---------------- per-node online-softmax attention ----------------
// One wave per dst node. 4 groups of 16 lanes; each group walks every 4th
// incoming edge with its own online-softmax state (m, den, num[4] f32 per lane
// = 64 channels per group). Cross-group merge via shfl_xor(16,32).
// `io` holds the skip projection on entry and the layer output on exit.

__global__ void attn_kernel(const float* __restrict__ q, const float* __restrict__ k,
                            const float* __restrict__ v,
                            const int* __restrict__ offs, const int* __restrict__ ssrc,
                            float* __restrict__ io, int n, int do_relu) {
    const int tid = threadIdx.x;
    const int lane = tid & 63;
    const int g = lane >> 4;
    const int gl = lane & 15;
    int node = blockIdx.x * (blockDim.x >> 6) + (tid >> 6);
    if (node >= n) return;
    int e0 = offs[node], e1 = offs[node + 1];
    float4 qv = *(const float4*)&q[(size_t)node * DCH + gl * 4];
    float m = -INFINITY, den = 0.f;
    float nx = 0.f, ny = 0.f, nz = 0.f, nw = 0.f;
    for (int e = e0 + g; e < e1; e += 4) {
        int src = ssrc[e];
        float4 kv = *(const float4*)&k[(size_t)src * DCH + gl * 4];
        float dot = qv.x*kv.x + qv.y*kv.y + qv.z*kv.z + qv.w*kv.w;
        dot += __shfl_xor(dot, 1);
        dot += __shfl_xor(dot, 2);
        dot += __shfl_xor(dot, 4);
        dot += __shfl_xor(dot, 8);
        float s = dot * 0.125f;           // 1/sqrt(64)
        float mn = fmaxf(m, s);
        float c = __expf(m - mn);         // first iter: exp(-inf) = 0
        float p = __expf(s - mn);
        float4 vv = *(const float4*)&v[(size_t)src * DCH + gl * 4];
        nx = nx * c + p * vv.x;
        ny = ny * c + p * vv.y;
        nz = nz * c + p * vv.z;
        nw = nw * c + p * vv.w;
        den = den * c + p;
        m = mn;
    }
    // merge the 4 group-partials (guard empty groups: den==0 -> weight 0)
    #pragma unroll
    for (int delta = 16; delta <= 32; delta <<= 1) {
        float mo   = __shfl_xor(m, delta);
        float deno = __shfl_xor(den, delta);
        float nxo  = __shfl_xor(nx, delta);
        float nyo  = __shfl_xor(ny, delta);
        float nzo  = __shfl_xor(nz, delta);
        float nwo  = __shfl_xor(nw, delta);
        float mn = fmaxf(m, mo);
        float c  = (den  > 0.f) ? __expf(m  - mn) : 0.f;
        float co = (deno > 0.f) ? __expf(mo - mn) : 0.f;
        nx = nx * c + nxo * co;
        ny = ny * c + nyo * co;
        nz = nz * c + nzo * co;
        nw = nw * c + nwo * co;
        den = den * c + deno * co;
        m = mn;
    }
    float4 skv = *(const float4*)&io[(size_t)node * DCH + gl * 4];
    float inv = (den > 0.f) ? 1.f / den : 0.f;   // empty node -> skip only
    float4 o;
    o.x = nx * inv + skv.x;
    o.y = ny * inv + skv.y;
    o.z = nz * inv + skv.z;
    o.w = nw * inv + skv.w;
    if (do_relu) {
        o.x = fmaxf(o.x, 0.f); o.y = fmaxf(o.y, 0.f);
        o.z = fmaxf(o.z, 0.f); o.w = fmaxf(o.w, 0.f);
    }
    if (lane < 16) *(float4*)&io[(size_t)node * DCH + gl * 4] = o;
}

// ---------------- launch ----------------

extern "C" void kernel_launch(void* const* d_in, const int* in_sizes, int n_in,
                              void* d_out, int out_size, void* d_ws, size_t ws_size,
                              hipStream_t stream) {
    const float* x   = (const float*)d_in[0];
    const int*   ei  = (const int*)d_in[1];      // int32 per harness contract
    const float* Wq1 = (const float*)d_in[2];  const float* bq1 = (const float*)d_in[3];
    const float* Wk1 = (const float*)d_in[4];  const float* bk1 = (const float*)d_in[5];
    const float* Wv1 = (const float*)d_in[6];  const float* bv1 = (const float*)d_in[7];
    const float* Ws1 = (const float*)d_in[8];  const float* bs1 = (const float*)d_in[9];
    const float* Wq2 = (const float*)d_in[10]; const float* bq2 = (const float*)d_in[11];
    const float* Wk2 = (const float*)d_in[12]; const float* bk2 = (const float*)d_in[13];
    const float* Wv2 = (const float*)d_in[14]; const float* bv2 = (const float*)d_in[15];
    const float* Ws2 = (const float*)d_in[16]; const float* bs2 = (const float*)d_in[17];
    int N = in_sizes[0] / DCH;
    int E = in_sizes[1] / 2;

    char* p = (char*)d_ws;
    auto alloc = [&](size_t bytes) -> void* {
        void* r = (void*)p; p += (bytes + 255) & ~(size_t)255; return r;
    };
    float* q    = (float*)alloc((size_t)N * DCH * 4);
    float* kbuf = (float*)alloc((size_t)N * DCH * 4);
    float* vbuf = (float*)alloc((size_t)N * DCH * 4);
    float* h    = (float*)alloc((size_t)N * DCH * 4);
    int* cnt  = (int*)alloc((size_t)N * 4);
    int* fill = (int*)alloc((size_t)N * 4);
    int* offs = (int*)alloc((size_t)(N + 1) * 4);
    int* part = (int*)alloc(1024 * 4);
    int* ssrc = (int*)alloc((size_t)E * 4);
    float* outp = (float*)d_out;

    int nb = (N + 1023) / 1024;

    // CSR by dst (rebuilt every call; ws is re-poisoned before each launch)
    hipLaunchKernelGGL(zero_kernel, dim3((N + 255) / 256), dim3(256), 0, stream, cnt, N);
    hipLaunchKernelGGL(zero_kernel, dim3((N + 255) / 256), dim3(256), 0, stream, fill, N);
    hipLaunchKernelGGL(hist_kernel, dim3(1024), dim3(256), 0, stream, ei, cnt, E);
    hipLaunchKernelGGL(scan1_kernel, dim3(nb), dim3(1024), 0, stream, cnt, offs, part, N);
    hipLaunchKernelGGL(scan2_kernel, dim3(1), dim3(1024), 0, stream, part, offs + N, nb);
    hipLaunchKernelGGL(scan3_kernel, dim3(nb), dim3(1024), 0, stream, offs, part, N);
    hipLaunchKernelGGL(scatter_kernel, dim3(1024), dim3(256), 0, stream, ei, offs, fill, ssrc, E);

    // layer 1 (skip -> h, attn updates h in place, ReLU)
    hipLaunchKernelGGL(linear4_kernel, dim3((N + 63) / 64), dim3(256), 0, stream,
                       x, Wq1, bq1, Wk1, bk1, Wv1, bv1, Ws1, bs1,
                       q, kbuf, vbuf, h, N);
    hipLaunchKernelGGL(attn_kernel, dim3((N + 3) / 4), dim3(256), 0, stream,
                       q, kbuf, vbuf, offs, ssrc, h, N, 1);

    // layer 2 (skip -> d_out, attn updates d_out in place)
    hipLaunchKernelGGL(linear4_kernel, dim3((N + 63) / 64), dim3(256), 0, stream,
                       h, Wq2, bq2, Wk2, bk2, Wv2, bv2, Ws2, bs2,
                       q, kbuf, vbuf, outp, N);
    hipLaunchKernelGGL(attn_kernel, dim3((N + 3) / 4), dim3(256), 0, stream,
                       q, kbuf, vbuf, offs, ssrc, outp, N, 0);
}

// Round 12
// 600.865 us; speedup vs baseline: 1.6902x; 1.6902x over previous
//
#include <hip/hip_runtime.h>
#include <math.h>

#define DCH 64

typedef __attribute__((ext_vector_type(8))) short short8v;  // 8 bf16 = 4 VGPRs
typedef __attribute__((ext_vector_type(4))) float f32x4;

__device__ __forceinline__ unsigned short f2bf(float f) {
    unsigned u = __builtin_bit_cast(unsigned, f);
    unsigned r = u + 0x7FFF + ((u >> 16) & 1);   // round-to-nearest-even
    return (unsigned short)(r >> 16);
}

// ---------------- CSR build ----------------
// edge_index arrives as int32 (harness converts int64 -> int32):
//   ei[e] = src, ei[E + e] = dst.

__global__ void zero_kernel(int* __restrict__ p, int n) {
    int i = blockIdx.x * blockDim.x + threadIdx.x;
    if (i < n) p[i] = 0;
}

__global__ void hist_kernel(const int* __restrict__ ei, int* __restrict__ cnt, int E) {
    int stride = gridDim.x * blockDim.x;
    for (int e = blockIdx.x * blockDim.x + threadIdx.x; e < E; e += stride) {
        int d = ei[(size_t)E + e];
        atomicAdd(&cnt[d], 1);
    }
}

__global__ void scan1_kernel(const int* __restrict__ cnt, int* __restrict__ offs,
                             int* __restrict__ partial, int n) {
    __shared__ int sh[1024];
    int i = blockIdx.x * 1024 + threadIdx.x;
    int val = (i < n) ? cnt[i] : 0;
    sh[threadIdx.x] = val;
    __syncthreads();
    for (int d = 1; d < 1024; d <<= 1) {
        int t = (threadIdx.x >= d) ? sh[threadIdx.x - d] : 0;
        __syncthreads();
        sh[threadIdx.x] += t;
        __syncthreads();
    }
    if (i < n) offs[i] = sh[threadIdx.x] - val;   // exclusive within block
    if (threadIdx.x == 1023) partial[blockIdx.x] = sh[1023];
}

__global__ void scan2_kernel(int* __restrict__ partial, int* __restrict__ total, int nb) {
    __shared__ int sh[1024];
    int val = (threadIdx.x < nb) ? partial[threadIdx.x] : 0;
    sh[threadIdx.x] = val;
    __syncthreads();
    for (int d = 1; d < 1024; d <<= 1) {
        int t = (threadIdx.x >= d) ? sh[threadIdx.x - d] : 0;
        __syncthreads();
        sh[threadIdx.x] += t;
        __syncthreads();
    }
    if (threadIdx.x < nb) partial[threadIdx.x] = sh[threadIdx.x] - val; // exclusive block offsets
    if (threadIdx.x == 1023) *total = sh[1023];
}

__global__ void scan3_kernel(int* __restrict__ offs, const int* __restrict__ partial, int n) {
    int i = blockIdx.x * 1024 + threadIdx.x;
    if (i < n) offs[i] += partial[blockIdx.x];
}

__global__ void scatter_kernel(const int* __restrict__ ei, const int* __restrict__ offs,
                               int* __restrict__ fill, int* __restrict__ ssrc, int E) {
    int stride = gridDim.x * blockDim.x;
    for (int e = blockIdx.x * blockDim.x + threadIdx.x; e < E; e += stride) {
        int s = ei[e];
        int d = ei[(size_t)E + e];
        int pos = offs[d] + atomicAdd(&fill[d], 1);
        ssrc[pos] = s;
    }
}

// ---------------- fused q/k/v/skip linear via MFMA ----------------
// Round-8 PMC: VALU linear4 = latency-bound (VALUBusy 21.7%, occ 19.6%,
// 443 GB/s, 12.5 TF) -> f32 VALU path caps ~100+ us. Switch to bf16 MFMA:
// X[100k x 64] @ [Wq|Wk|Wv|Ws]^T, f32 accumulate, f32 bias.
// Block = 4 waves, wave = matrix, 64 nodes/block. No LDS, no barriers.
// mfma_f32_16x16x32_bf16 layouts (HW-verified m89/m91):
//   A[16x32]: row=lane&15, k=8*(lane>>4)+j  (8 consecutive bf16 per lane)
//   B[32x16]: k=8*(lane>>4)+j, col=lane&15  (B[k][c]=W[c][k] -> read W rows)
//   C/D:      col=lane&15, row=(lane>>4)*4+reg
// Store instr = 4 rows x 64 B full sectors (coalesced, proven in round 8).

__global__ __launch_bounds__(256, 3)
void linear4_kernel(const float* __restrict__ x,
                    const float* __restrict__ Wq, const float* __restrict__ bq,
                    const float* __restrict__ Wk, const float* __restrict__ bk,
                    const float* __restrict__ Wv, const float* __restrict__ bv,
                    const float* __restrict__ Ws, const float* __restrict__ bs,
                    float* __restrict__ oq, float* __restrict__ ok,
                    float* __restrict__ ov, float* __restrict__ os,
                    int n) {
    const int tid = threadIdx.x;
    const int w = tid >> 6;        // wave -> matrix
    const int lane = tid & 63;
    const int l16 = lane & 15;
    const int lhi = lane >> 4;     // 0..3
    const float* W; const float* b; float* o;
    if (w == 0)      { W = Wq; b = bq; o = oq; }
    else if (w == 1) { W = Wk; b = bk; o = ok; }
    else if (w == 2) { W = Wv; b = bv; o = ov; }
    else             { W = Ws; b = bs; o = os; }
    const int base = blockIdx.x * 64;

    // B fragments for this wave's matrix: nt = out-ch quad, ks = K-step.
    short8v Bf[4][2];
    #pragma unroll
    for (int nt = 0; nt < 4; ++nt) {
        const float* wrow = W + (size_t)(nt * 16 + l16) * DCH;
        #pragma unroll
        for (int ks = 0; ks < 2; ++ks) {
            const float4* wp = (const float4*)(wrow + ks * 32 + lhi * 8);
            float4 lo = wp[0], hi = wp[1];
            short8v f;
            f[0] = (short)f2bf(lo.x); f[1] = (short)f2bf(lo.y);
            f[2] = (short)f2bf(lo.z); f[3] = (short)f2bf(lo.w);
            f[4] = (short)f2bf(hi.x); f[5] = (short)f2bf(hi.y);
            f[6] = (short)f2bf(hi.z); f[7] = (short)f2bf(hi.w);
            Bf[nt][ks] = f;
        }
    }
    float bv4[4];
    #pragma unroll
    for (int nt = 0; nt < 4; ++nt) bv4[nt] = b[nt * 16 + l16];

    f32x4 acc[4][4];
    #pragma unroll
    for (int mt = 0; mt < 4; ++mt)
        #pragma unroll
        for (int nt = 0; nt < 4; ++nt)
            acc[mt][nt] = (f32x4)0.f;

    #pragma unroll
    for (int mt = 0; mt < 4; ++mt) {
        int row = base + mt * 16 + l16;
        if (row > n - 1) row = n - 1;            // clamp loads; stores guarded
        const float* xp = x + (size_t)row * DCH + lhi * 8;
        float4 a0 = *(const float4*)xp;
        float4 a1 = *(const float4*)(xp + 4);
        float4 a2 = *(const float4*)(xp + 32);
        float4 a3 = *(const float4*)(xp + 36);
        short8v A0, A1;
        A0[0] = (short)f2bf(a0.x); A0[1] = (short)f2bf(a0.y);
        A0[2] = (short)f2bf(a0.z); A0[3] = (short)f2bf(a0.w);
        A0[4] = (short)f2bf(a1.x); A0[5] = (short)f2bf(a1.y);
        A0[6] = (short)f2bf(a1.z); A0[7] = (short)f2bf(a1.w);
        A1[0] = (short)f2bf(a2.x); A1[1] = (short)f2bf(a2.y);
        A1[2] = (short)f2bf(a2.z); A1[3] = (short)f2bf(a2.w);
        A1[4] = (short)f2bf(a3.x); A1[5] = (short)f2bf(a3.y);
        A1[6] = (short)f2bf(a3.z); A1[7] = (short)f2bf(a3.w);
        #pragma unroll
        for (int nt = 0; nt < 4; ++nt) {
            acc[mt][nt] = __builtin_amdgcn_mfma_f32_16x16x32_bf16(
                A0, Bf[nt][0], acc[mt][nt], 0, 0, 0);
            acc[mt][nt] = __builtin_amdgcn_mfma_f32_16x16x32_bf16(
                A1, Bf[nt][1], acc[mt][nt], 0, 0, 0);
        }
    }

    #pragma unroll
    for (int mt = 0; mt < 4; ++mt) {
        #pragma unroll
        for (int r = 0; r < 4; ++r) {
            int row = base + mt * 16 + lhi * 4 + r;
            if (row < n) {
                #pragma unroll
                for (int nt = 0; nt < 4; ++nt)
                    o[(size_t)row * DCH + nt * 16 + l16] = acc[mt][nt][r] + bv4[nt];
            }
        }
    }
}

// ---------------- per-node online-softmax attention ----------------
// One wave per dst node. 4 groups of 16 lanes; each group walks every 4th
// incoming edge with its own online-softmax state (m, den, num[4] f32 per lane
// = 64 channels per group). Cross-group merge via shfl_xor(16,32).
// `io` holds the skip projection on entry and the layer output on exit.

__global__ void attn_kernel(const float* __restrict__ q, const float* __restrict__ k,
                            const float* __restrict__ v,
                            const int* __restrict__ offs, const int* __restrict__ ssrc,
                            float* __restrict__ io, int n, int do_relu) {
    const int tid = threadIdx.x;
    const int lane = tid & 63;
    const int g = lane >> 4;
    const int gl = lane & 15;
    int node = blockIdx.x * (blockDim.x >> 6) + (tid >> 6);
    if (node >= n) return;
    int e0 = offs[node], e1 = offs[node + 1];
    float4 qv = *(const float4*)&q[(size_t)node * DCH + gl * 4];
    float m = -INFINITY, den = 0.f;
    float nx = 0.f, ny = 0.f, nz = 0.f, nw = 0.f;
    for (int e = e0 + g; e < e1; e += 4) {
        int src = ssrc[e];
        float4 kv = *(const float4*)&k[(size_t)src * DCH + gl * 4];
        float dot = qv.x*kv.x + qv.y*kv.y + qv.z*kv.z + qv.w*kv.w;
        dot += __shfl_xor(dot, 1);
        dot += __shfl_xor(dot, 2);
        dot += __shfl_xor(dot, 4);
        dot += __shfl_xor(dot, 8);
        float s = dot * 0.125f;           // 1/sqrt(64)
        float mn = fmaxf(m, s);
        float c = __expf(m - mn);         // first iter: exp(-inf) = 0
        float p = __expf(s - mn);
        float4 vv = *(const float4*)&v[(size_t)src * DCH + gl * 4];
        nx = nx * c + p * vv.x;
        ny = ny * c + p * vv.y;
        nz = nz * c + p * vv.z;
        nw = nw * c + p * vv.w;
        den = den * c + p;
        m = mn;
    }
    // merge the 4 group-partials (guard empty groups: den==0 -> weight 0)
    #pragma unroll
    for (int delta = 16; delta <= 32; delta <<= 1) {
        float mo   = __shfl_xor(m, delta);
        float deno = __shfl_xor(den, delta);
        float nxo  = __shfl_xor(nx, delta);
        float nyo  = __shfl_xor(ny, delta);
        float nzo  = __shfl_xor(nz, delta);
        float nwo  = __shfl_xor(nw, delta);
        float mn = fmaxf(m, mo);
        float c  = (den  > 0.f) ? __expf(m  - mn) : 0.f;
        float co = (deno > 0.f) ? __expf(mo - mn) : 0.f;
        nx = nx * c + nxo * co;
        ny = ny * c + nyo * co;
        nz = nz * c + nzo * co;
        nw = nw * c + nwo * co;
        den = den * c + deno * co;
        m = mn;
    }
    float4 skv = *(const float4*)&io[(size_t)node * DCH + gl * 4];
    float inv = (den > 0.f) ? 1.f / den : 0.f;   // empty node -> skip only
    float4 o;
    o.x = nx * inv + skv.x;
    o.y = ny * inv + skv.y;
    o.z = nz * inv + skv.z;
    o.w = nw * inv + skv.w;
    if (do_relu) {
        o.x = fmaxf(o.x, 0.f); o.y = fmaxf(o.y, 0.f);
        o.z = fmaxf(o.z, 0.f); o.w = fmaxf(o.w, 0.f);
    }
    if (lane < 16) *(float4*)&io[(size_t)node * DCH + gl * 4] = o;
}

// ---------------- launch ----------------

extern "C" void kernel_launch(void* const* d_in, const int* in_sizes, int n_in,
                              void* d_out, int out_size, void* d_ws, size_t ws_size,
                              hipStream_t stream) {
    const float* x   = (const float*)d_in[0];
    const int*   ei  = (const int*)d_in[1];      // int32 per harness contract
    const float* Wq1 = (const float*)d_in[2];  const float* bq1 = (const float*)d_in[3];
    const float* Wk1 = (const float*)d_in[4];  const float* bk1 = (const float*)d_in[5];
    const float* Wv1 = (const float*)d_in[6];  const float* bv1 = (const float*)d_in[7];
    const float* Ws1 = (const float*)d_in[8];  const float* bs1 = (const float*)d_in[9];
    const float* Wq2 = (const float*)d_in[10]; const float* bq2 = (const float*)d_in[11];
    const float* Wk2 = (const float*)d_in[12]; const float* bk2 = (const float*)d_in[13];
    const float* Wv2 = (const float*)d_in[14]; const float* bv2 = (const float*)d_in[15];
    const float* Ws2 = (const float*)d_in[16]; const float* bs2 = (const float*)d_in[17];
    int N = in_sizes[0] / DCH;
    int E = in_sizes[1] / 2;

    char* p = (char*)d_ws;
    auto alloc = [&](size_t bytes) -> void* {
        void* r = (void*)p; p += (bytes + 255) & ~(size_t)255; return r;
    };
    float* q    = (float*)alloc((size_t)N * DCH * 4);
    float* kbuf = (float*)alloc((size_t)N * DCH * 4);
    float* vbuf = (float*)alloc((size_t)N * DCH * 4);
    float* h    = (float*)alloc((size_t)N * DCH * 4);
    int* cnt  = (int*)alloc((size_t)N * 4);
    int* fill = (int*)alloc((size_t)N * 4);
    int* offs = (int*)alloc((size_t)(N + 1) * 4);
    int* part = (int*)alloc(1024 * 4);
    int* ssrc = (int*)alloc((size_t)E * 4);
    float* outp = (float*)d_out;

    int nb = (N + 1023) / 1024;

    // CSR by dst (rebuilt every call; ws is re-poisoned before each launch)
    hipLaunchKernelGGL(zero_kernel, dim3((N + 255) / 256), dim3(256), 0, stream, cnt, N);
    hipLaunchKernelGGL(zero_kernel, dim3((N + 255) / 256), dim3(256), 0, stream, fill, N);
    hipLaunchKernelGGL(hist_kernel, dim3(1024), dim3(256), 0, stream, ei, cnt, E);
    hipLaunchKernelGGL(scan1_kernel, dim3(nb), dim3(1024), 0, stream, cnt, offs, part, N);
    hipLaunchKernelGGL(scan2_kernel, dim3(1), dim3(1024), 0, stream, part, offs + N, nb);
    hipLaunchKernelGGL(scan3_kernel, dim3(nb), dim3(1024), 0, stream, offs, part, N);
    hipLaunchKernelGGL(scatter_kernel, dim3(1024), dim3(256), 0, stream, ei, offs, fill, ssrc, E);

    // layer 1 (skip -> h, attn updates h in place, ReLU)
    hipLaunchKernelGGL(linear4_kernel, dim3((N + 63) / 64), dim3(256), 0, stream,
                       x, Wq1, bq1, Wk1, bk1, Wv1, bv1, Ws1, bs1,
                       q, kbuf, vbuf, h, N);
    hipLaunchKernelGGL(attn_kernel, dim3((N + 3) / 4), dim3(256), 0, stream,
                       q, kbuf, vbuf, offs, ssrc, h, N, 1);

    // layer 2 (skip -> d_out, attn updates d_out in place)
    hipLaunchKernelGGL(linear4_kernel, dim3((N + 63) / 64), dim3(256), 0, stream,
                       h, Wq2, bq2, Wk2, bk2, Wv2, bv2, Ws2, bs2,
                       q, kbuf, vbuf, outp, N);
    hipLaunchKernelGGL(attn_kernel, dim3((N + 3) / 4), dim3(256), 0, stream,
                       q, kbuf, vbuf, offs, ssrc, outp, N, 0);
}

// Round 16
// 548.654 us; speedup vs baseline: 1.8510x; 1.0952x over previous
//
#include <hip/hip_runtime.h>
#include <math.h>

#define DCH 64

typedef __attribute__((ext_vector_type(8))) short short8v;  // 8 bf16 = 4 VGPRs
typedef __attribute__((ext_vector_type(4))) float f32x4;

__device__ __forceinline__ unsigned short f2bf(float f) {
    unsigned u = __builtin_bit_cast(unsigned, f);
    unsigned r = u + 0x7FFF + ((u >> 16) & 1);   // round-to-nearest-even
    return (unsigned short)(r >> 16);
}
__device__ __forceinline__ float bflo(unsigned u) {
    return __builtin_bit_cast(float, u << 16);
}
__device__ __forceinline__ float bfhi(unsigned u) {
    return __builtin_bit_cast(float, u & 0xFFFF0000u);
}

// ---------------- CSR build ----------------
// edge_index arrives as int32: ei[e] = src, ei[E + e] = dst.

__global__ void zero_kernel(int* __restrict__ p, int n) {
    int i = blockIdx.x * blockDim.x + threadIdx.x;
    if (i < n) p[i] = 0;
}

__global__ void hist_kernel(const int* __restrict__ ei, int* __restrict__ cnt, int E) {
    int stride = gridDim.x * blockDim.x;
    for (int e = blockIdx.x * blockDim.x + threadIdx.x; e < E; e += stride) {
        int d = ei[(size_t)E + e];
        atomicAdd(&cnt[d], 1);
    }
}

__global__ void scan1_kernel(const int* __restrict__ cnt, int* __restrict__ offs,
                             int* __restrict__ partial, int n) {
    __shared__ int sh[1024];
    int i = blockIdx.x * 1024 + threadIdx.x;
    int val = (i < n) ? cnt[i] : 0;
    sh[threadIdx.x] = val;
    __syncthreads();
    for (int d = 1; d < 1024; d <<= 1) {
        int t = (threadIdx.x >= d) ? sh[threadIdx.x - d] : 0;
        __syncthreads();
        sh[threadIdx.x] += t;
        __syncthreads();
    }
    if (i < n) offs[i] = sh[threadIdx.x] - val;   // exclusive within block
    if (threadIdx.x == 1023) partial[blockIdx.x] = sh[1023];
}

__global__ void scan2_kernel(int* __restrict__ partial, int* __restrict__ total, int nb) {
    __shared__ int sh[1024];
    int val = (threadIdx.x < nb) ? partial[threadIdx.x] : 0;
    sh[threadIdx.x] = val;
    __syncthreads();
    for (int d = 1; d < 1024; d <<= 1) {
        int t = (threadIdx.x >= d) ? sh[threadIdx.x - d] : 0;
        __syncthreads();
        sh[threadIdx.x] += t;
        __syncthreads();
    }
    if (threadIdx.x < nb) partial[threadIdx.x] = sh[threadIdx.x] - val; // exclusive block offsets
    if (threadIdx.x == 1023) *total = sh[1023];
}

__global__ void scan3_kernel(int* __restrict__ offs, const int* __restrict__ partial, int n) {
    int i = blockIdx.x * 1024 + threadIdx.x;
    if (i < n) offs[i] += partial[blockIdx.x];
}

// Scatter consumes offs in place: atomicAdd turns offs[d] into the segment END.
// attn then uses e0 = (node ? offs[node-1] : 0), e1 = offs[node].
__global__ void scatter_kernel(const int* __restrict__ ei, int* __restrict__ offs,
                               int* __restrict__ ssrc, int E) {
    int stride = gridDim.x * blockDim.x;
    for (int e = blockIdx.x * blockDim.x + threadIdx.x; e < E; e += stride) {
        int s = ei[e];
        int d = ei[(size_t)E + e];
        int pos = atomicAdd(&offs[d], 1);
        ssrc[pos] = s;
    }
}

// ---------------- fused q/k/v/skip linear via MFMA ----------------
// bf16 MFMA, f32 accumulate (round-12: absmax 0.0078, linear4 ~<60 us).
// q,skip -> f32 outputs (plain channel map, 64-B-sector stores).
// k,v -> bf16 outputs for attn's gathers (halves per-edge gather bytes).
//   To keep stores sector-aligned with 2-B elements, k/v waves use the
//   interleaved channel map ch(nt,c) = 2c + (nt&1) + 32*(nt>>1): lane c holds
//   adjacent channel pairs -> pack 2 bf16/dword -> 16 lanes x 4 B = 64 B.

__global__ __launch_bounds__(256, 3)
void linear4_kernel(const float* __restrict__ x,
                    const float* __restrict__ Wq, const float* __restrict__ bq,
                    const float* __restrict__ Wk, const float* __restrict__ bk,
                    const float* __restrict__ Wv, const float* __restrict__ bv,
                    const float* __restrict__ Ws, const float* __restrict__ bs,
                    float* __restrict__ oq, unsigned short* __restrict__ ok,
                    unsigned short* __restrict__ ov, float* __restrict__ os,
                    int n) {
    const int tid = threadIdx.x;
    const int w = tid >> 6;        // wave -> matrix
    const int lane = tid & 63;
    const int l16 = lane & 15;
    const int lhi = lane >> 4;     // 0..3
    const bool isbf = (w == 1) || (w == 2);
    const float* W; const float* b;
    if (w == 0)      { W = Wq; b = bq; }
    else if (w == 1) { W = Wk; b = bk; }
    else if (w == 2) { W = Wv; b = bv; }
    else             { W = Ws; b = bs; }
    const int base = blockIdx.x * 64;

    // B fragments: channel of (nt, l16) depends on output dtype mapping.
    int ch[4];
    #pragma unroll
    for (int nt = 0; nt < 4; ++nt)
        ch[nt] = isbf ? (2 * l16 + (nt & 1) + 32 * (nt >> 1)) : (nt * 16 + l16);

    short8v Bf[4][2];
    #pragma unroll
    for (int nt = 0; nt < 4; ++nt) {
        const float* wrow = W + (size_t)ch[nt] * DCH;
        #pragma unroll
        for (int ks = 0; ks < 2; ++ks) {
            const float4* wp = (const float4*)(wrow + ks * 32 + lhi * 8);
            float4 lo = wp[0], hi = wp[1];
            short8v f;
            f[0] = (short)f2bf(lo.x); f[1] = (short)f2bf(lo.y);
            f[2] = (short)f2bf(lo.z); f[3] = (short)f2bf(lo.w);
            f[4] = (short)f2bf(hi.x); f[5] = (short)f2bf(hi.y);
            f[6] = (short)f2bf(hi.z); f[7] = (short)f2bf(hi.w);
            Bf[nt][ks] = f;
        }
    }
    float bv4[4];
    #pragma unroll
    for (int nt = 0; nt < 4; ++nt) bv4[nt] = b[ch[nt]];

    f32x4 acc[4][4];
    #pragma unroll
    for (int mt = 0; mt < 4; ++mt)
        #pragma unroll
        for (int nt = 0; nt < 4; ++nt)
            acc[mt][nt] = (f32x4)0.f;

    #pragma unroll
    for (int mt = 0; mt < 4; ++mt) {
        int row = base + mt * 16 + l16;
        if (row > n - 1) row = n - 1;            // clamp loads; stores guarded
        const float* xp = x + (size_t)row * DCH + lhi * 8;
        float4 a0 = *(const float4*)xp;
        float4 a1 = *(const float4*)(xp + 4);
        float4 a2 = *(const float4*)(xp + 32);
        float4 a3 = *(const float4*)(xp + 36);
        short8v A0, A1;
        A0[0] = (short)f2bf(a0.x); A0[1] = (short)f2bf(a0.y);
        A0[2] = (short)f2bf(a0.z); A0[3] = (short)f2bf(a0.w);
        A0[4] = (short)f2bf(a1.x); A0[5] = (short)f2bf(a1.y);
        A0[6] = (short)f2bf(a1.z); A0[7] = (short)f2bf(a1.w);
        A1[0] = (short)f2bf(a2.x); A1[1] = (short)f2bf(a2.y);
        A1[2] = (short)f2bf(a2.z); A1[3] = (short)f2bf(a2.w);
        A1[4] = (short)f2bf(a3.x); A1[5] = (short)f2bf(a3.y);
        A1[6] = (short)f2bf(a3.z); A1[7] = (short)f2bf(a3.w);
        #pragma unroll
        for (int nt = 0; nt < 4; ++nt) {
            acc[mt][nt] = __builtin_amdgcn_mfma_f32_16x16x32_bf16(
                A0, Bf[nt][0], acc[mt][nt], 0, 0, 0);
            acc[mt][nt] = __builtin_amdgcn_mfma_f32_16x16x32_bf16(
                A1, Bf[nt][1], acc[mt][nt], 0, 0, 0);
        }
    }

    if (isbf) {
        unsigned short* o = (w == 1) ? ok : ov;
        #pragma unroll
        for (int mt = 0; mt < 4; ++mt) {
            #pragma unroll
            for (int r = 0; r < 4; ++r) {
                int row = base + mt * 16 + lhi * 4 + r;
                if (row < n) {
                    unsigned p0 = (unsigned)f2bf(acc[mt][0][r] + bv4[0])
                                | ((unsigned)f2bf(acc[mt][1][r] + bv4[1]) << 16);
                    unsigned p1 = (unsigned)f2bf(acc[mt][2][r] + bv4[2])
                                | ((unsigned)f2bf(acc[mt][3][r] + bv4[3]) << 16);
                    unsigned short* rp = o + (size_t)row * DCH;
                    *(unsigned*)(rp + 2 * l16)      = p0;   // ch 2l16, 2l16+1
                    *(unsigned*)(rp + 32 + 2 * l16) = p1;   // ch 32+2l16, +1
                }
            }
        }
    } else {
        float* o = (w == 0) ? oq : os;
        #pragma unroll
        for (int mt = 0; mt < 4; ++mt) {
            #pragma unroll
            for (int r = 0; r < 4; ++r) {
                int row = base + mt * 16 + lhi * 4 + r;
                if (row < n) {
                    #pragma unroll
                    for (int nt = 0; nt < 4; ++nt)
                        o[(size_t)row * DCH + nt * 16 + l16] = acc[mt][nt][r] + bv4[nt];
                }
            }
        }
    }
}

// ---------------- per-node online-softmax attention ----------------
// One wave per dst node; 4 groups of 16 lanes walk interleaved edges with
// online-softmax state; cross-group merge via shfl_xor(16,32).
// k,v are bf16 (128 B/row gathers). offs holds segment ENDS (post-scatter).
// `io` holds the skip projection on entry and the layer output on exit.

__global__ void attn_kernel(const float* __restrict__ q,
                            const unsigned short* __restrict__ k,
                            const unsigned short* __restrict__ v,
                            const int* __restrict__ offs, const int* __restrict__ ssrc,
                            float* __restrict__ io, int n, int do_relu) {
    const int tid = threadIdx.x;
    const int lane = tid & 63;
    const int g = lane >> 4;
    const int gl = lane & 15;
    int node = blockIdx.x * (blockDim.x >> 6) + (tid >> 6);
    if (node >= n) return;
    int e0 = (node > 0) ? offs[node - 1] : 0;
    int e1 = offs[node];
    float4 qv = *(const float4*)&q[(size_t)node * DCH + gl * 4];
    float m = -INFINITY, den = 0.f;
    float nx = 0.f, ny = 0.f, nz = 0.f, nw = 0.f;
    for (int e = e0 + g; e < e1; e += 4) {
        int src = ssrc[e];
        uint2 kk = *(const uint2*)(k + (size_t)src * DCH + gl * 4);
        float dot = qv.x * bflo(kk.x) + qv.y * bfhi(kk.x)
                  + qv.z * bflo(kk.y) + qv.w * bfhi(kk.y);
        dot += __shfl_xor(dot, 1);
        dot += __shfl_xor(dot, 2);
        dot += __shfl_xor(dot, 4);
        dot += __shfl_xor(dot, 8);
        float s = dot * 0.125f;           // 1/sqrt(64)
        float mn = fmaxf(m, s);
        float c = __expf(m - mn);         // first iter: exp(-inf) = 0
        float p = __expf(s - mn);
        uint2 vv = *(const uint2*)(v + (size_t)src * DCH + gl * 4);
        nx = nx * c + p * bflo(vv.x);
        ny = ny * c + p * bfhi(vv.x);
        nz = nz * c + p * bflo(vv.y);
        nw = nw * c + p * bfhi(vv.y);
        den = den * c + p;
        m = mn;
    }
    // merge the 4 group-partials (guard empty groups: den==0 -> weight 0)
    #pragma unroll
    for (int delta = 16; delta <= 32; delta <<= 1) {
        float mo   = __shfl_xor(m, delta);
        float deno = __shfl_xor(den, delta);
        float nxo  = __shfl_xor(nx, delta);
        float nyo  = __shfl_xor(ny, delta);
        float nzo  = __shfl_xor(nz, delta);
        float nwo  = __shfl_xor(nw, delta);
        float mn = fmaxf(m, mo);
        float c  = (den  > 0.f) ? __expf(m  - mn) : 0.f;
        float co = (deno > 0.f) ? __expf(mo - mn) : 0.f;
        nx = nx * c + nxo * co;
        ny = ny * c + nyo * co;
        nz = nz * c + nzo * co;
        nw = nw * c + nwo * co;
        den = den * c + deno * co;
        m = mn;
    }
    float4 skv = *(const float4*)&io[(size_t)node * DCH + gl * 4];
    float inv = (den > 0.f) ? 1.f / den : 0.f;   // empty node -> skip only
    float4 o;
    o.x = nx * inv + skv.x;
    o.y = ny * inv + skv.y;
    o.z = nz * inv + skv.z;
    o.w = nw * inv + skv.w;
    if (do_relu) {
        o.x = fmaxf(o.x, 0.f); o.y = fmaxf(o.y, 0.f);
        o.z = fmaxf(o.z, 0.f); o.w = fmaxf(o.w, 0.f);
    }
    if (lane < 16) *(float4*)&io[(size_t)node * DCH + gl * 4] = o;
}

// ---------------- launch ----------------

extern "C" void kernel_launch(void* const* d_in, const int* in_sizes, int n_in,
                              void* d_out, int out_size, void* d_ws, size_t ws_size,
                              hipStream_t stream) {
    const float* x   = (const float*)d_in[0];
    const int*   ei  = (const int*)d_in[1];      // int32 per harness contract
    const float* Wq1 = (const float*)d_in[2];  const float* bq1 = (const float*)d_in[3];
    const float* Wk1 = (const float*)d_in[4];  const float* bk1 = (const float*)d_in[5];
    const float* Wv1 = (const float*)d_in[6];  const float* bv1 = (const float*)d_in[7];
    const float* Ws1 = (const float*)d_in[8];  const float* bs1 = (const float*)d_in[9];
    const float* Wq2 = (const float*)d_in[10]; const float* bq2 = (const float*)d_in[11];
    const float* Wk2 = (const float*)d_in[12]; const float* bk2 = (const float*)d_in[13];
    const float* Wv2 = (const float*)d_in[14]; const float* bv2 = (const float*)d_in[15];
    const float* Ws2 = (const float*)d_in[16]; const float* bs2 = (const float*)d_in[17];
    int N = in_sizes[0] / DCH;
    int E = in_sizes[1] / 2;

    char* p = (char*)d_ws;
    auto alloc = [&](size_t bytes) -> void* {
        void* r = (void*)p; p += (bytes + 255) & ~(size_t)255; return r;
    };
    float*          q    = (float*)alloc((size_t)N * DCH * 4);
    unsigned short* kbuf = (unsigned short*)alloc((size_t)N * DCH * 2);
    unsigned short* vbuf = (unsigned short*)alloc((size_t)N * DCH * 2);
    float*          h    = (float*)alloc((size_t)N * DCH * 4);
    int* cnt  = (int*)alloc((size_t)N * 4);
    int* offs = (int*)alloc((size_t)(N + 1) * 4);
    int* part = (int*)alloc(1024 * 4);
    int* ssrc = (int*)alloc((size_t)E * 4);
    float* outp = (float*)d_out;

    int nb = (N + 1023) / 1024;

    // CSR by dst (rebuilt every call; ws is re-poisoned before each launch)
    hipLaunchKernelGGL(zero_kernel, dim3((N + 255) / 256), dim3(256), 0, stream, cnt, N);
    hipLaunchKernelGGL(hist_kernel, dim3(1024), dim3(256), 0, stream, ei, cnt, E);
    hipLaunchKernelGGL(scan1_kernel, dim3(nb), dim3(1024), 0, stream, cnt, offs, part, N);
    hipLaunchKernelGGL(scan2_kernel, dim3(1), dim3(1024), 0, stream, part, offs + N, nb);
    hipLaunchKernelGGL(scan3_kernel, dim3(nb), dim3(1024), 0, stream, offs, part, N);
    hipLaunchKernelGGL(scatter_kernel, dim3(1024), dim3(256), 0, stream, ei, offs, ssrc, E);

    // layer 1 (skip -> h, attn updates h in place, ReLU)
    hipLaunchKernelGGL(linear4_kernel, dim3((N + 63) / 64), dim3(256), 0, stream,
                       x, Wq1, bq1, Wk1, bk1, Wv1, bv1, Ws1, bs1,
                       q, kbuf, vbuf, h, N);
    hipLaunchKernelGGL(attn_kernel, dim3((N + 3) / 4), dim3(256), 0, stream,
                       q, kbuf, vbuf, offs, ssrc, h, N, 1);

    // layer 2 (skip -> d_out, attn updates d_out in place)
    hipLaunchKernelGGL(linear4_kernel, dim3((N + 63) / 64), dim3(256), 0, stream,
                       h, Wq2, bq2, Wk2, bk2, Wv2, bv2, Ws2, bs2,
                       q, kbuf, vbuf, outp, N);
    hipLaunchKernelGGL(attn_kernel, dim3((N + 3) / 4), dim3(256), 0, stream,
                       q, kbuf, vbuf, offs, ssrc, outp, N, 0);
}

// Round 17
// 483.031 us; speedup vs baseline: 2.1025x; 1.1359x over previous
//
#include <hip/hip_runtime.h>
#include <math.h>

#define DCH 64

typedef __attribute__((ext_vector_type(8))) short short8v;  // 8 bf16 = 4 VGPRs
typedef __attribute__((ext_vector_type(4))) float f32x4;

__device__ __forceinline__ unsigned short f2bf(float f) {
    unsigned u = __builtin_bit_cast(unsigned, f);
    unsigned r = u + 0x7FFF + ((u >> 16) & 1);   // round-to-nearest-even
    return (unsigned short)(r >> 16);
}
__device__ __forceinline__ float bflo(unsigned u) {
    return __builtin_bit_cast(float, u << 16);
}
__device__ __forceinline__ float bfhi(unsigned u) {
    return __builtin_bit_cast(float, u & 0xFFFF0000u);
}

// ---------------- CSR build ----------------
// edge_index arrives as int32: ei[e] = src, ei[E + e] = dst.
// Round-16 PMC: scatter WRITE_SIZE = 106 MB for a 6.4 MB payload (E x 64 B):
// random 4B writes from all 8 non-coherent XCD L2s -> one masked partial
// sector writeback per write. Fix: dst-range partitioning with XCD-affine
// block groups (g = blockIdx & 7 ~ XCD g under round-robin dispatch). Range
// g's ssrc segment (~0.8 MB) is then written by ONE XCD only -> lines fill
// completely in its 4 MB L2 -> ~full-line writebacks. Costs 8x re-read of
// the dst array (sequential, L3-resident). Correctness does not depend on
// the XCD mapping heuristic.

__global__ void zero_kernel(int* __restrict__ p, int n) {
    int i = blockIdx.x * blockDim.x + threadIdx.x;
    if (i < n) p[i] = 0;
}

__global__ void hist_kernel(const int* __restrict__ ei, int* __restrict__ cnt,
                            int E, int n) {
    const int grp = blockIdx.x & 7;
    const int bid = blockIdx.x >> 3;
    const int nbg = gridDim.x >> 3;
    const int chunk = (n + 7) >> 3;
    const int lo = grp * chunk;
    const int hi = (lo + chunk < n) ? lo + chunk : n;
    int stride = nbg * blockDim.x;
    for (int e = bid * blockDim.x + threadIdx.x; e < E; e += stride) {
        int d = ei[(size_t)E + e];
        if (d >= lo && d < hi) atomicAdd(&cnt[d], 1);
    }
}

__global__ void scan1_kernel(const int* __restrict__ cnt, int* __restrict__ offs,
                             int* __restrict__ partial, int n) {
    __shared__ int sh[1024];
    int i = blockIdx.x * 1024 + threadIdx.x;
    int val = (i < n) ? cnt[i] : 0;
    sh[threadIdx.x] = val;
    __syncthreads();
    for (int d = 1; d < 1024; d <<= 1) {
        int t = (threadIdx.x >= d) ? sh[threadIdx.x - d] : 0;
        __syncthreads();
        sh[threadIdx.x] += t;
        __syncthreads();
    }
    if (i < n) offs[i] = sh[threadIdx.x] - val;   // exclusive within block
    if (threadIdx.x == 1023) partial[blockIdx.x] = sh[1023];
}

__global__ void scan2_kernel(int* __restrict__ partial, int* __restrict__ total, int nb) {
    __shared__ int sh[1024];
    int val = (threadIdx.x < nb) ? partial[threadIdx.x] : 0;
    sh[threadIdx.x] = val;
    __syncthreads();
    for (int d = 1; d < 1024; d <<= 1) {
        int t = (threadIdx.x >= d) ? sh[threadIdx.x - d] : 0;
        __syncthreads();
        sh[threadIdx.x] += t;
        __syncthreads();
    }
    if (threadIdx.x < nb) partial[threadIdx.x] = sh[threadIdx.x] - val; // exclusive block offsets
    if (threadIdx.x == 1023) *total = sh[1023];
}

__global__ void scan3_kernel(int* __restrict__ offs, const int* __restrict__ partial, int n) {
    int i = blockIdx.x * 1024 + threadIdx.x;
    if (i < n) offs[i] += partial[blockIdx.x];
}

// Scatter consumes offs in place: atomicAdd turns offs[d] into the segment END.
// attn then uses e0 = (node ? offs[node-1] : 0), e1 = offs[node].
// XCD-affine dst-range partitioning as in hist_kernel.
__global__ void scatter_kernel(const int* __restrict__ ei, int* __restrict__ offs,
                               int* __restrict__ ssrc, int E, int n) {
    const int grp = blockIdx.x & 7;
    const int bid = blockIdx.x >> 3;
    const int nbg = gridDim.x >> 3;
    const int chunk = (n + 7) >> 3;
    const int lo = grp * chunk;
    const int hi = (lo + chunk < n) ? lo + chunk : n;
    int stride = nbg * blockDim.x;
    for (int e = bid * blockDim.x + threadIdx.x; e < E; e += stride) {
        int d = ei[(size_t)E + e];
        if (d >= lo && d < hi) {
            int s = ei[e];
            int pos = atomicAdd(&offs[d], 1);
            ssrc[pos] = s;
        }
    }
}

// ---------------- fused q/k/v/skip linear via MFMA ----------------
// bf16 MFMA, f32 accumulate (round-12: absmax 0.0078, linear4 ~<60 us).
// q,skip -> f32 outputs (plain channel map, 64-B-sector stores).
// k,v -> bf16 outputs for attn's gathers (halves per-edge gather bytes).
//   Interleaved channel map ch(nt,c) = 2c + (nt&1) + 32*(nt>>1) keeps bf16
//   stores sector-aligned (verified round 16: absmax 0.0078).

__global__ __launch_bounds__(256, 3)
void linear4_kernel(const float* __restrict__ x,
                    const float* __restrict__ Wq, const float* __restrict__ bq,
                    const float* __restrict__ Wk, const float* __restrict__ bk,
                    const float* __restrict__ Wv, const float* __restrict__ bv,
                    const float* __restrict__ Ws, const float* __restrict__ bs,
                    float* __restrict__ oq, unsigned short* __restrict__ ok,
                    unsigned short* __restrict__ ov, float* __restrict__ os,
                    int n) {
    const int tid = threadIdx.x;
    const int w = tid >> 6;        // wave -> matrix
    const int lane = tid & 63;
    const int l16 = lane & 15;
    const int lhi = lane >> 4;     // 0..3
    const bool isbf = (w == 1) || (w == 2);
    const float* W; const float* b;
    if (w == 0)      { W = Wq; b = bq; }
    else if (w == 1) { W = Wk; b = bk; }
    else if (w == 2) { W = Wv; b = bv; }
    else             { W = Ws; b = bs; }
    const int base = blockIdx.x * 64;

    // B fragments: channel of (nt, l16) depends on output dtype mapping.
    int ch[4];
    #pragma unroll
    for (int nt = 0; nt < 4; ++nt)
        ch[nt] = isbf ? (2 * l16 + (nt & 1) + 32 * (nt >> 1)) : (nt * 16 + l16);

    short8v Bf[4][2];
    #pragma unroll
    for (int nt = 0; nt < 4; ++nt) {
        const float* wrow = W + (size_t)ch[nt] * DCH;
        #pragma unroll
        for (int ks = 0; ks < 2; ++ks) {
            const float4* wp = (const float4*)(wrow + ks * 32 + lhi * 8);
            float4 lo = wp[0], hi = wp[1];
            short8v f;
            f[0] = (short)f2bf(lo.x); f[1] = (short)f2bf(lo.y);
            f[2] = (short)f2bf(lo.z); f[3] = (short)f2bf(lo.w);
            f[4] = (short)f2bf(hi.x); f[5] = (short)f2bf(hi.y);
            f[6] = (short)f2bf(hi.z); f[7] = (short)f2bf(hi.w);
            Bf[nt][ks] = f;
        }
    }
    float bv4[4];
    #pragma unroll
    for (int nt = 0; nt < 4; ++nt) bv4[nt] = b[ch[nt]];

    f32x4 acc[4][4];
    #pragma unroll
    for (int mt = 0; mt < 4; ++mt)
        #pragma unroll
        for (int nt = 0; nt < 4; ++nt)
            acc[mt][nt] = (f32x4)0.f;

    #pragma unroll
    for (int mt = 0; mt < 4; ++mt) {
        int row = base + mt * 16 + l16;
        if (row > n - 1) row = n - 1;            // clamp loads; stores guarded
        const float* xp = x + (size_t)row * DCH + lhi * 8;
        float4 a0 = *(const float4*)xp;
        float4 a1 = *(const float4*)(xp + 4);
        float4 a2 = *(const float4*)(xp + 32);
        float4 a3 = *(const float4*)(xp + 36);
        short8v A0, A1;
        A0[0] = (short)f2bf(a0.x); A0[1] = (short)f2bf(a0.y);
        A0[2] = (short)f2bf(a0.z); A0[3] = (short)f2bf(a0.w);
        A0[4] = (short)f2bf(a1.x); A0[5] = (short)f2bf(a1.y);
        A0[6] = (short)f2bf(a1.z); A0[7] = (short)f2bf(a1.w);
        A1[0] = (short)f2bf(a2.x); A1[1] = (short)f2bf(a2.y);
        A1[2] = (short)f2bf(a2.z); A1[3] = (short)f2bf(a2.w);
        A1[4] = (short)f2bf(a3.x); A1[5] = (short)f2bf(a3.y);
        A1[6] = (short)f2bf(a3.z); A1[7] = (short)f2bf(a3.w);
        #pragma unroll
        for (int nt = 0; nt < 4; ++nt) {
            acc[mt][nt] = __builtin_amdgcn_mfma_f32_16x16x32_bf16(
                A0, Bf[nt][0], acc[mt][nt], 0, 0, 0);
            acc[mt][nt] = __builtin_amdgcn_mfma_f32_16x16x32_bf16(
                A1, Bf[nt][1], acc[mt][nt], 0, 0, 0);
        }
    }

    if (isbf) {
        unsigned short* o = (w == 1) ? ok : ov;
        #pragma unroll
        for (int mt = 0; mt < 4; ++mt) {
            #pragma unroll
            for (int r = 0; r < 4; ++r) {
                int row = base + mt * 16 + lhi * 4 + r;
                if (row < n) {
                    unsigned p0 = (unsigned)f2bf(acc[mt][0][r] + bv4[0])
                                | ((unsigned)f2bf(acc[mt][1][r] + bv4[1]) << 16);
                    unsigned p1 = (unsigned)f2bf(acc[mt][2][r] + bv4[2])
                                | ((unsigned)f2bf(acc[mt][3][r] + bv4[3]) << 16);
                    unsigned short* rp = o + (size_t)row * DCH;
                    *(unsigned*)(rp + 2 * l16)      = p0;   // ch 2l16, 2l16+1
                    *(unsigned*)(rp + 32 + 2 * l16) = p1;   // ch 32+2l16, +1
                }
            }
        }
    } else {
        float* o = (w == 0) ? oq : os;
        #pragma unroll
        for (int mt = 0; mt < 4; ++mt) {
            #pragma unroll
            for (int r = 0; r < 4; ++r) {
                int row = base + mt * 16 + lhi * 4 + r;
                if (row < n) {
                    #pragma unroll
                    for (int nt = 0; nt < 4; ++nt)
                        o[(size_t)row * DCH + nt * 16 + l16] = acc[mt][nt][r] + bv4[nt];
                }
            }
        }
    }
}

// ---------------- per-node online-softmax attention ----------------
// One wave per dst node; 4 groups of 16 lanes walk interleaved edges with
// online-softmax state; cross-group merge via shfl_xor(16,32).
// k,v are bf16 (128 B/row gathers). offs holds segment ENDS (post-scatter).
// `io` holds the skip projection on entry and the layer output on exit.

__global__ void attn_kernel(const float* __restrict__ q,
                            const unsigned short* __restrict__ k,
                            const unsigned short* __restrict__ v,
                            const int* __restrict__ offs, const int* __restrict__ ssrc,
                            float* __restrict__ io, int n, int do_relu) {
    const int tid = threadIdx.x;
    const int lane = tid & 63;
    const int g = lane >> 4;
    const int gl = lane & 15;
    int node = blockIdx.x * (blockDim.x >> 6) + (tid >> 6);
    if (node >= n) return;
    int e0 = (node > 0) ? offs[node - 1] : 0;
    int e1 = offs[node];
    float4 qv = *(const float4*)&q[(size_t)node * DCH + gl * 4];
    float m = -INFINITY, den = 0.f;
    float nx = 0.f, ny = 0.f, nz = 0.f, nw = 0.f;
    for (int e = e0 + g; e < e1; e += 4) {
        int src = ssrc[e];
        uint2 kk = *(const uint2*)(k + (size_t)src * DCH + gl * 4);
        float dot = qv.x * bflo(kk.x) + qv.y * bfhi(kk.x)
                  + qv.z * bflo(kk.y) + qv.w * bfhi(kk.y);
        dot += __shfl_xor(dot, 1);
        dot += __shfl_xor(dot, 2);
        dot += __shfl_xor(dot, 4);
        dot += __shfl_xor(dot, 8);
        float s = dot * 0.125f;           // 1/sqrt(64)
        float mn = fmaxf(m, s);
        float c = __expf(m - mn);         // first iter: exp(-inf) = 0
        float p = __expf(s - mn);
        uint2 vv = *(const uint2*)(v + (size_t)src * DCH + gl * 4);
        nx = nx * c + p * bflo(vv.x);
        ny = ny * c + p * bfhi(vv.x);
        nz = nz * c + p * bflo(vv.y);
        nw = nw * c + p * bfhi(vv.y);
        den = den * c + p;
        m = mn;
    }
    // merge the 4 group-partials (guard empty groups: den==0 -> weight 0)
    #pragma unroll
    for (int delta = 16; delta <= 32; delta <<= 1) {
        float mo   = __shfl_xor(m, delta);
        float deno = __shfl_xor(den, delta);
        float nxo  = __shfl_xor(nx, delta);
        float nyo  = __shfl_xor(ny, delta);
        float nzo  = __shfl_xor(nz, delta);
        float nwo  = __shfl_xor(nw, delta);
        float mn = fmaxf(m, mo);
        float c  = (den  > 0.f) ? __expf(m  - mn) : 0.f;
        float co = (deno > 0.f) ? __expf(mo - mn) : 0.f;
        nx = nx * c + nxo * co;
        ny = ny * c + nyo * co;
        nz = nz * c + nzo * co;
        nw = nw * c + nwo * co;
        den = den * c + deno * co;
        m = mn;
    }
    float4 skv = *(const float4*)&io[(size_t)node * DCH + gl * 4];
    float inv = (den > 0.f) ? 1.f / den : 0.f;   // empty node -> skip only
    float4 o;
    o.x = nx * inv + skv.x;
    o.y = ny * inv + skv.y;
    o.z = nz * inv + skv.z;
    o.w = nw * inv + skv.w;
    if (do_relu) {
        o.x = fmaxf(o.x, 0.f); o.y = fmaxf(o.y, 0.f);
        o.z = fmaxf(o.z, 0.f); o.w = fmaxf(o.w, 0.f);
    }
    if (lane < 16) *(float4*)&io[(size_t)node * DCH + gl * 4] = o;
}

// ---------------- launch ----------------

extern "C" void kernel_launch(void* const* d_in, const int* in_sizes, int n_in,
                              void* d_out, int out_size, void* d_ws, size_t ws_size,
                              hipStream_t stream) {
    const float* x   = (const float*)d_in[0];
    const int*   ei  = (const int*)d_in[1];      // int32 per harness contract
    const float* Wq1 = (const float*)d_in[2];  const float* bq1 = (const float*)d_in[3];
    const float* Wk1 = (const float*)d_in[4];  const float* bk1 = (const float*)d_in[5];
    const float* Wv1 = (const float*)d_in[6];  const float* bv1 = (const float*)d_in[7];
    const float* Ws1 = (const float*)d_in[8];  const float* bs1 = (const float*)d_in[9];
    const float* Wq2 = (const float*)d_in[10]; const float* bq2 = (const float*)d_in[11];
    const float* Wk2 = (const float*)d_in[12]; const float* bk2 = (const float*)d_in[13];
    const float* Wv2 = (const float*)d_in[14]; const float* bv2 = (const float*)d_in[15];
    const float* Ws2 = (const float*)d_in[16]; const float* bs2 = (const float*)d_in[17];
    int N = in_sizes[0] / DCH;
    int E = in_sizes[1] / 2;

    char* p = (char*)d_ws;
    auto alloc = [&](size_t bytes) -> void* {
        void* r = (void*)p; p += (bytes + 255) & ~(size_t)255; return r;
    };
    float*          q    = (float*)alloc((size_t)N * DCH * 4);
    unsigned short* kbuf = (unsigned short*)alloc((size_t)N * DCH * 2);
    unsigned short* vbuf = (unsigned short*)alloc((size_t)N * DCH * 2);
    float*          h    = (float*)alloc((size_t)N * DCH * 4);
    int* cnt  = (int*)alloc((size_t)N * 4);
    int* offs = (int*)alloc((size_t)(N + 1) * 4);
    int* part = (int*)alloc(1024 * 4);
    int* ssrc = (int*)alloc((size_t)E * 4);
    float* outp = (float*)d_out;

    int nb = (N + 1023) / 1024;

    // CSR by dst (rebuilt every call; ws is re-poisoned before each launch)
    hipLaunchKernelGGL(zero_kernel, dim3((N + 255) / 256), dim3(256), 0, stream, cnt, N);
    hipLaunchKernelGGL(hist_kernel, dim3(1024), dim3(256), 0, stream, ei, cnt, E, N);
    hipLaunchKernelGGL(scan1_kernel, dim3(nb), dim3(1024), 0, stream, cnt, offs, part, N);
    hipLaunchKernelGGL(scan2_kernel, dim3(1), dim3(1024), 0, stream, part, offs + N, nb);
    hipLaunchKernelGGL(scan3_kernel, dim3(nb), dim3(1024), 0, stream, offs, part, N);
    hipLaunchKernelGGL(scatter_kernel, dim3(1024), dim3(256), 0, stream, ei, offs, ssrc, E, N);

    // layer 1 (skip -> h, attn updates h in place, ReLU)
    hipLaunchKernelGGL(linear4_kernel, dim3((N + 63) / 64), dim3(256), 0, stream,
                       x, Wq1, bq1, Wk1, bk1, Wv1, bv1, Ws1, bs1,
                       q, kbuf, vbuf, h, N);
    hipLaunchKernelGGL(attn_kernel, dim3((N + 3) / 4), dim3(256), 0, stream,
                       q, kbuf, vbuf, offs, ssrc, h, N, 1);

    // layer 2 (skip -> d_out, attn updates d_out in place)
    hipLaunchKernelGGL(linear4_kernel, dim3((N + 63) / 64), dim3(256), 0, stream,
                       h, Wq2, bq2, Wk2, bk2, Wv2, bv2, Ws2, bs2,
                       q, kbuf, vbuf, outp, N);
    hipLaunchKernelGGL(attn_kernel, dim3((N + 3) / 4), dim3(256), 0, stream,
                       q, kbuf, vbuf, offs, ssrc, outp, N, 0);
}